// Round 1
// baseline (2044.246 us; speedup 1.0000x reference)
//
#include <hip/hip_runtime.h>

typedef __bf16 bf16_t;
typedef bf16_t bf16x8 __attribute__((ext_vector_type(8)));
typedef float f32x4 __attribute__((ext_vector_type(4)));

typedef const __attribute__((address_space(1))) void* as1cv;
typedef __attribute__((address_space(3))) void* as3v;

#define DEVINL __device__ __forceinline__

constexpr int N_PTS = 65536;

static_assert(sizeof(bf16x8) == 16, "bf16x8 must be 16B");

DEVINL ushort f2bs(float x) {
  unsigned u = __builtin_bit_cast(unsigned, x);
  return (ushort)((u + 0x7fffu + ((u >> 16) & 1u)) >> 16);  // RNE
}
DEVINL float bs2f(ushort s) {
  unsigned u = ((unsigned)s) << 16;
  return __builtin_bit_cast(float, u);
}

// ---------------- prep: data f32 -> bf16 ----------------
__global__ __launch_bounds__(256) void cvt_data_k(const float* __restrict__ in,
                                                  ushort* __restrict__ out) {
  int i = (blockIdx.x * 256 + threadIdx.x) * 4;
  float4 v = *reinterpret_cast<const float4*>(in + i);
  ushort4 o;
  o.x = f2bs(v.x); o.y = f2bs(v.y); o.z = f2bs(v.z); o.w = f2bs(v.w);
  *reinterpret_cast<ushort4*>(out + i) = o;
}

// ---------------- prep: transpose weights to (N,K) bf16 ----------------
__global__ __launch_bounds__(256) void prep_w_k(const float* __restrict__ Wqkv,
                                                const float* __restrict__ Wproj,
                                                ushort* __restrict__ WqkvT,
                                                ushort* __restrict__ WprojT) {
  int idx = blockIdx.x * 256 + threadIdx.x;  // < 1048576
  if (idx < 512 * 1536) {
    int k = idx / 1536, n = idx - k * 1536;
    WqkvT[n * 512 + k] = f2bs(Wqkv[idx]);
  } else {
    int i2 = idx - 512 * 1536;
    int k = i2 >> 9, n = i2 & 511;
    WprojT[n * 512 + k] = f2bs(Wproj[i2]);
  }
}

// ---------------- GEMM (B^T input), K=512, 128x128 tile, m97 structure ----------------
// ROPE epilogue: each wave owns a 64-aligned 64-col extent == one (which,h) block,
// so rope pair (hd, hd+32) lives in acc frags (nf, nf+2) of the SAME lane.
template <int NC, bool ROPE>
__global__ __launch_bounds__(256) void gemm_bt_k(
    const ushort* __restrict__ A,    // M x 512 bf16
    const ushort* __restrict__ Bt,   // NC x 512 bf16
    const float* __restrict__ bias,  // NC
    const float* __restrict__ xyz,   // N x 3 (ROPE only)
    const float* __restrict__ freqs, // 8 x 32 x 3 (ROPE only)
    ushort* __restrict__ Obf,        // bf16 out (ROPE)
    float* __restrict__ Of)          // f32 out (!ROPE)
{
  __shared__ alignas(16) ushort sA[128 * 32];
  __shared__ alignas(16) ushort sB[128 * 32];
  const int tid  = threadIdx.x;
  const int lane = tid & 63;
  const int w    = tid >> 6;
  const int wm = w >> 1, wn = w & 1;
  const int tileM = blockIdx.x * 128;
  const int tileN = blockIdx.y * 128;

  f32x4 acc[4][4] = {};

  // staging: 512 chunks of 16B per tile; chunk ck = it*256 + tid
  const int r0 = tid >> 2;
  const int kb = (tid & 3) << 3;
  const ushort* gA0 = A  + (size_t)(tileM + r0) * 512 + kb;
  const ushort* gB0 = Bt + (size_t)(tileN + r0) * 512 + kb;
  const ushort* gA1 = A  + (size_t)(tileM + r0 + 64) * 512 + kb;
  const ushort* gB1 = Bt + (size_t)(tileN + r0 + 64) * 512 + kb;
  ushort* lA0 = &sA[(w * 64) * 8];          // wave-uniform base, lane*16B auto
  ushort* lB0 = &sB[(w * 64) * 8];
  ushort* lA1 = &sA[(256 + w * 64) * 8];
  ushort* lB1 = &sB[(256 + w * 64) * 8];

  for (int k0 = 0; k0 < 512; k0 += 32) {
    __builtin_amdgcn_global_load_lds((as1cv)(gA0 + k0), (as3v)lA0, 16, 0, 0);
    __builtin_amdgcn_global_load_lds((as1cv)(gB0 + k0), (as3v)lB0, 16, 0, 0);
    __builtin_amdgcn_global_load_lds((as1cv)(gA1 + k0), (as3v)lA1, 16, 0, 0);
    __builtin_amdgcn_global_load_lds((as1cv)(gB1 + k0), (as3v)lB1, 16, 0, 0);
    __syncthreads();  // compiler drains vmcnt before s_barrier

    const int krow = (lane >> 4) * 8;
    bf16x8 af[4], bfr[4];
#pragma unroll
    for (int i = 0; i < 4; ++i) {
      af[i]  = *reinterpret_cast<const bf16x8*>(&sA[(wm * 64 + i * 16 + (lane & 15)) * 32 + krow]);
      bfr[i] = *reinterpret_cast<const bf16x8*>(&sB[(wn * 64 + i * 16 + (lane & 15)) * 32 + krow]);
    }
#pragma unroll
    for (int i = 0; i < 4; ++i)
#pragma unroll
      for (int j = 0; j < 4; ++j)
        acc[i][j] = __builtin_amdgcn_mfma_f32_16x16x32_bf16(af[i], bfr[j], acc[i][j], 0, 0, 0);
    __syncthreads();
  }

  // epilogue: C layout col = lane&15, row = (lane>>4)*4 + reg
  const int cl   = lane & 15;
  const int rb   = (lane >> 4) * 4;
  const int wrow = tileM + wm * 64;
  const int wcol = tileN + wn * 64;
  float bsv[4];
#pragma unroll
  for (int nf = 0; nf < 4; ++nf) bsv[nf] = bias[wcol + nf * 16 + cl];

  if constexpr (ROPE) {
    const int which = wcol >> 9;
    if (which < 2) {
      const int h = (wcol >> 6) & 7;
      const float* fp0 = freqs + (h * 32 + cl) * 3;
      const float* fp1 = freqs + (h * 32 + 16 + cl) * 3;
      const float f00 = fp0[0], f01 = fp0[1], f02 = fp0[2];
      const float f10 = fp1[0], f11 = fp1[1], f12 = fp1[2];
#pragma unroll
      for (int mf = 0; mf < 4; ++mf) {
#pragma unroll
        for (int r = 0; r < 4; ++r) {
          const int m = wrow + mf * 16 + rb + r;
          const float x0 = xyz[3 * m + 0], x1 = xyz[3 * m + 1], x2 = xyz[3 * m + 2];
          const float th0 = x0 * f00 + x1 * f01 + x2 * f02;
          const float th1 = x0 * f10 + x1 * f11 + x2 * f12;
          const float s0 = sinf(th0), c0 = cosf(th0);
          const float s1 = sinf(th1), c1 = cosf(th1);
          const float v0 = acc[mf][0][r] + bsv[0];
          const float v1 = acc[mf][1][r] + bsv[1];
          const float v2 = acc[mf][2][r] + bsv[2];
          const float v3 = acc[mf][3][r] + bsv[3];
          ushort* orow = Obf + (size_t)m * NC + wcol;
          orow[cl]      = f2bs(v0 * c0 - v2 * s0);
          orow[16 + cl] = f2bs(v1 * c1 - v3 * s1);
          orow[32 + cl] = f2bs(v0 * s0 + v2 * c0);
          orow[48 + cl] = f2bs(v1 * s1 + v3 * c1);
        }
      }
    } else {  // v: no rope
#pragma unroll
      for (int mf = 0; mf < 4; ++mf)
#pragma unroll
        for (int r = 0; r < 4; ++r) {
          const int m = wrow + mf * 16 + rb + r;
          ushort* orow = Obf + (size_t)m * NC + wcol;
#pragma unroll
          for (int nf = 0; nf < 4; ++nf) orow[nf * 16 + cl] = f2bs(acc[mf][nf][r] + bsv[nf]);
        }
    }
  } else {
#pragma unroll
    for (int mf = 0; mf < 4; ++mf)
#pragma unroll
      for (int r = 0; r < 4; ++r) {
        const int m = wrow + mf * 16 + rb + r;
        float* orow = Of + (size_t)m * NC + wcol;
#pragma unroll
        for (int nf = 0; nf < 4; ++nf) orow[nf * 16 + cl] = acc[mf][nf][r] + bsv[nf];
      }
  }
}

// ---------------- windowed attention: one wave per (window b, head h) ----------------
__global__ __launch_bounds__(64) void attn_win_k(const ushort* __restrict__ qkv,  // N x 1536 bf16
                                                 const float* __restrict__ mask,  // B x 24 x 24
                                                 ushort* __restrict__ outa)       // N x 512 bf16
{
  __shared__ float sq[24][68];
  __shared__ float sk[24][68];
  __shared__ float sv[24][68];
  __shared__ float sS[24][25];
  const int bid = blockIdx.x;
  const int b = bid >> 3, h = bid & 7;
  const int g = b >> 2, dw = b & 3;
  const int lane  = threadIdx.x;
  const int nbase = g * 96 + dw - 12;  // + ki*4 (dilated window, minus PAD)

  for (int ki = 0; ki < 24; ++ki) {
    int n = nbase + ki * 4;
    float q, k, v;
    if (n < 0) { q = k = v = -1.0f; }                 // head pad rows are -1.0
    else if (n >= N_PTS) { q = k = v = 0.0f; }        // tail pad rows are 0
    else {
      const ushort* p = qkv + (size_t)n * 1536 + h * 64 + lane;
      q = bs2f(p[0]); k = bs2f(p[512]); v = bs2f(p[1024]);
    }
    sq[ki][lane] = q; sk[ki][lane] = k; sv[ki][lane] = v;
  }
  __syncthreads();

  // scores: 576 entries over 64 lanes x 9
  for (int j = 0; j < 9; ++j) {
    int e = j * 64 + lane;
    int qi = e / 24, ki = e - qi * 24;
    float s = 0.f;
#pragma unroll
    for (int d = 0; d < 64; ++d) s = fmaf(sq[qi][d], sk[ki][d], s);
    sS[qi][ki] = s * 0.125f + mask[(size_t)b * 576 + e];  // scale = 64^-0.5
  }
  __syncthreads();

  if (lane < 24) {  // per-row softmax; masked (-1000) entries underflow to 0 in expf
    float mx = -3.4e38f;
#pragma unroll
    for (int k2 = 0; k2 < 24; ++k2) mx = fmaxf(mx, sS[lane][k2]);
    float sum = 0.f;
#pragma unroll
    for (int k2 = 0; k2 < 24; ++k2) { float t = expf(sS[lane][k2] - mx); sum += t; sS[lane][k2] = t; }
    float inv = 1.0f / sum;
#pragma unroll
    for (int k2 = 0; k2 < 24; ++k2) sS[lane][k2] *= inv;
  }
  __syncthreads();

  // PV: lane = dim
  for (int qi = 0; qi < 24; ++qi) {
    int n = nbase + qi * 4;
    if (n < 0 || n >= N_PTS) continue;  // pad query rows discarded
    float o = 0.f;
#pragma unroll
    for (int ki = 0; ki < 24; ++ki) o = fmaf(sS[qi][ki], sv[ki][lane], o);
    outa[(size_t)n * 512 + h * 64 + lane] = f2bs(o);
  }
}

extern "C" void kernel_launch(void* const* d_in, const int* in_sizes, int n_in,
                              void* d_out, int out_size, void* d_ws, size_t ws_size,
                              hipStream_t stream) {
  const float* data  = (const float*)d_in[0];
  const float* xyz   = (const float*)d_in[1];
  const float* mask  = (const float*)d_in[2];
  const float* Wqkv  = (const float*)d_in[3];
  const float* bqkv  = (const float*)d_in[4];
  const float* Wproj = (const float*)d_in[5];
  const float* bproj = (const float*)d_in[6];
  const float* freqs = (const float*)d_in[7];
  float* out = (float*)d_out;

  char* ws = (char*)d_ws;
  // layout: qkv (192MB) | data_bf16 / attn_out alias (64MB) | WqkvT (1.5MB) | WprojT (0.5MB)
  ushort* qkv_ws = (ushort*)ws;                                  // 65536*1536
  ushort* dat_bf = (ushort*)(ws + (size_t)201326592);            // 65536*512, reused as attn out
  ushort* WqkvT  = (ushort*)(ws + (size_t)268435456);            // 1536*512
  ushort* WprojT = (ushort*)(ws + (size_t)270008320);            // 512*512

  cvt_data_k<<<32768, 256, 0, stream>>>(data, dat_bf);
  prep_w_k<<<4096, 256, 0, stream>>>(Wqkv, Wproj, WqkvT, WprojT);
  gemm_bt_k<1536, true><<<dim3(512, 12), 256, 0, stream>>>(dat_bf, WqkvT, bqkv, xyz, freqs, qkv_ws, nullptr);
  attn_win_k<<<21856, 64, 0, stream>>>(qkv_ws, mask, dat_bf);
  gemm_bt_k<512, false><<<dim3(512, 4), 256, 0, stream>>>(dat_bf, WprojT, bproj, nullptr, nullptr, nullptr, out);
}